// Round 5
// baseline (5540.549 us; speedup 1.0000x reference)
//
#include <hip/hip_runtime.h>

#define TT 1000
#define FF 20
#define HH 256
#define OO 200
#define ZR 256           // zero-row index in padded tables (257 rows x 256 cols)
#define DSTR 68          // padded lane-stride (int64) for delta buffers: bank-conflict-free

typedef unsigned int uint;
typedef unsigned long long ull;

__device__ __forceinline__ int rfl(int v) { return __builtin_amdgcn_readfirstlane(v); }
__device__ __forceinline__ ull mku(ull v) {
    uint lo = (uint)rfl((int)(uint)v), hi = (uint)rfl((int)(uint)(v >> 32));
    return ((ull)hi << 32) | lo;
}

// Extract up to K rows from 64-bit toggle mask m (wave-uniform) and issue the
// 2K 16B loads (dual table, shared row stream). Empty slots hit zero row ZR.
// Tables are BIASED uint (q ^ 0x80000000 = q + 2^31): accumulate is plain
// u64 += u32 (2 VALU ops/elem), de-biased once per call via row counts.
template<int K>
__device__ __forceinline__ void loadK(const uint* __restrict__ tabA, const uint* __restrict__ tabB,
                                      ull& m, int rowbase, int cx, uint4* va, uint4* vb) {
    int rows[K];
#pragma unroll
    for (int u = 0; u < K; ++u) {
        int k = __ffsll(m) - 1;
        rows[u] = rfl(m ? (rowbase + k) : ZR);
        m &= (m - 1);
    }
#pragma unroll
    for (int u = 0; u < K; ++u) {
        size_t off = ((size_t)rows[u] << 8) + (size_t)cx;
        va[u] = *(const uint4*)(tabA + off);
        vb[u] = *(const uint4*)(tabB + off);
    }
}

template<int K>
__device__ __forceinline__ void accK(const uint4* va, const uint4* vb, ull* aA, ull* aB) {
#pragma unroll
    for (int u = 0; u < K; ++u) {
        aA[0] += va[u].x; aA[1] += va[u].y; aA[2] += va[u].z; aA[3] += va[u].w;
        aB[0] += vb[u].x; aB[1] += vb[u].y; aB[2] += vb[u].z; aB[3] += vb[u].w;
    }
}

// Dual-table gather over 64-bit toggle mask. Pos/neg split at mask level
// (pm = toggled-on rows: add; nm = toggled-off rows: subtract). First pos and
// neg batches are BOTH issued before either accumulates -> one load-latency
// exposure in the common case. Commit via LDS u64 atomics (exact mod-2^64).
__device__ __forceinline__ void gatherPair(const uint* __restrict__ tabA, const uint* __restrict__ tabB,
                                           ull tog, ull cur, int rowbase, int lane,
                                           long long* dstA, long long* dstB) {
    ull pm = tog & cur;
    ull nm = tog & ~cur;
    ull pA[4] = {0,0,0,0}, pB[4] = {0,0,0,0};
    ull nA[4] = {0,0,0,0}, nB[4] = {0,0,0,0};
    int cntP = 0, cntN = 0;
    const int cx = lane << 2;

    uint4 s0a[8], s0b[8], s1a[8], s1b[8];
    bool p8 = false, n8 = false;
    if (pm) {
        if (__popcll(pm) > 4) { loadK<8>(tabA, tabB, pm, rowbase, cx, s0a, s0b); p8 = true; cntP = 8; }
        else                  { loadK<4>(tabA, tabB, pm, rowbase, cx, s0a, s0b); cntP = 4; }
    }
    if (nm) {
        if (__popcll(nm) > 4) { loadK<8>(tabA, tabB, nm, rowbase, cx, s1a, s1b); n8 = true; cntN = 8; }
        else                  { loadK<4>(tabA, tabB, nm, rowbase, cx, s1a, s1b); cntN = 4; }
    }
    if (cntP) { if (p8) accK<8>(s0a, s0b, pA, pB); else accK<4>(s0a, s0b, pA, pB); }
    if (cntN) { if (n8) accK<8>(s1a, s1b, nA, nB); else accK<4>(s1a, s1b, nA, nB); }
    while (pm) {   // rare heavy tail
        if (__popcll(pm) > 4) { loadK<8>(tabA, tabB, pm, rowbase, cx, s0a, s0b); accK<8>(s0a, s0b, pA, pB); cntP += 8; }
        else                  { loadK<4>(tabA, tabB, pm, rowbase, cx, s0a, s0b); accK<4>(s0a, s0b, pA, pB); cntP += 4; }
    }
    while (nm) {
        if (__popcll(nm) > 4) { loadK<8>(tabA, tabB, nm, rowbase, cx, s1a, s1b); accK<8>(s1a, s1b, nA, nB); cntN += 8; }
        else                  { loadK<4>(tabA, tabB, nm, rowbase, cx, s1a, s1b); accK<4>(s1a, s1b, nA, nB); cntN += 4; }
    }
    // de-bias: every processed row (incl. zero-row padding) carried +2^31/elem
    ull bias = (ull)((long long)(cntP - cntN) << 31);
#pragma unroll
    for (int c = 0; c < 4; ++c) {
        atomicAdd((ull*)&dstA[c * DSTR + lane], pA[c] - nA[c] - bias);
        atomicAdd((ull*)&dstB[c * DSTR + lane], pB[c] - nB[c] - bias);
    }
}

#define INV30 9.31322574615478515625e-10   // 2^-30, exact

// 9-wave (576-thread) SINGLE-barrier pipeline (structure as round 4).
// Rotating zeroed delta buffers (2 slots): gather(i) atomic-adds into slot i&1;
// consumers fold slot (i-1)&1 into REGISTER totals and zero it.
// Waves 0-3: L1 update(i) + ballot (regs) + dual gather (W2Tq,V1q) + wx(i+1).
// Waves 4-7: L2 update(i-1) + ballot + dual gather (WTq,V2q).
// Wave 8: x(i+2) prefetch + output layer F(i-2).
__global__ __launch_bounds__(576, 1) void snn_main(
    const float* __restrict__ x,
    const float* __restrict__ W1, const float* __restrict__ b1,
    const float* __restrict__ beta1,
    const float* __restrict__ b2, const float* __restrict__ beta2,
    const uint* __restrict__ V1q, const uint* __restrict__ V2q,
    const uint* __restrict__ W2Tq, const uint* __restrict__ WTq,
    const float* __restrict__ alpha_out, const float* __restrict__ beta_out,
    float* __restrict__ out)
{
    __shared__ float xts[2][FF];                       // x[t] double buffer
    // delta buffers: drive d (0=V1 1=W2 2=V2 3=O) x slot p x [c][lane] (stride DSTR)
    __shared__ __align__(16) long long dAll[4 * 2 * 4 * DSTR];   // ~17 KB

#define DSL(d, p) (dAll + (((d) * 2 + (p)) * 4) * DSTR)

    const int tid  = threadIdx.x;
    const int wid  = tid >> 6;
    const int lane = tid & 63;
    const int b    = blockIdx.x;
    const float* xg = x + (size_t)b * TT * FF;

    // ---- init ----
    for (int idx = tid; idx < 4 * 2 * 4 * DSTR; idx += 576) dAll[idx] = 0;
    if (tid < FF) { xts[0][tid] = xg[tid]; xts[1][tid] = xg[FF + tid]; }

    // L1 state (tid 0..255): W1 row in registers, drive total in register
    float syn1 = 0.f, mem1 = 0.f, beta1r = 0.f, b1r = 0.f, wxv = 0.f;
    float w1r[FF];
    long long TV1 = 0;
    bool spk1 = false;
    ull cur1 = 0ull;
    if (tid < HH) {
        beta1r = beta1[tid]; b1r = b1[tid];
#pragma unroll
        for (int f = 0; f < FF; ++f) w1r[f] = W1[tid * FF + f];
    }

    // L2 state (tid 256..511)
    float syn2 = 0.f, mem2 = 0.f, beta2r = 0.f, b2r = 0.f;
    long long TW2 = 0, TV2 = 0;
    bool spk2 = false;
    ull cur2 = 0ull;
    if (wid >= 4 && wid < 8) { beta2r = beta2[tid - HH]; b2r = b2[tid - HH]; }

    // output state (wave 8)
    float synO[4] = {0,0,0,0}, memO[4] = {0,0,0,0}, accO[4] = {0,0,0,0};
    float aOr[4] = {0,0,0,0}, bOr[4] = {0,0,0,0};
    long long TOq[4] = {0, 0, 0, 0};
    bool  spkO[4] = {false,false,false,false};
    if (wid == 8) {
#pragma unroll
        for (int r = 0; r < 4; ++r) {
            int o = lane + (r << 6);
            if (o < OO) { aOr[r] = alpha_out[o]; bOr[r] = beta_out[o]; }
        }
    }
    __syncthreads();
    if (tid < HH) {   // wx for t=0
        float wx = b1r;
#pragma unroll
        for (int f = 0; f < FF; ++f) wx = fmaf(xts[0][f], w1r[f], wx);
        wxv = wx;
    }
    __syncthreads();  // protect xts[0] before wave-8's interval-0 rewrite

    for (int i = 0; i < TT + 2; ++i) {
        const int rp = (i - 1) & 1;   // fold slot (written last interval)
        const int wp = i & 1;         // gather-commit slot
        if (wid < 4) {
            // ---- L1: update(i) + gather + wx(i+1) ----
            if (i < TT) {
                long long* slot = DSL(0, rp);
                int idx = (tid & 3) * DSTR + (tid >> 2);
                TV1 += slot[idx]; slot[idx] = 0;
                float g1 = (float)((double)TV1 * INV30);
                syn1 = fmaf(0.95f, syn1, wxv + g1);
                mem1 = fmaf(beta1r, mem1, syn1) - (spk1 ? 1.f : 0.f);
                spk1 = mem1 > 1.0f;
                ull bal = __ballot(spk1 ? 1 : 0);
                ull tog = cur1 ^ bal;
                cur1 = bal;
                if (tog) gatherPair(W2Tq, V1q, mku(tog), mku(cur1), wid << 6, lane,
                                    DSL(1, wp), DSL(0, wp));
                if ((i + 1) < TT) {
                    const float* xx = xts[(i + 1) & 1];
                    float wx = b1r;
#pragma unroll
                    for (int f = 0; f < FF; ++f) wx = fmaf(xx[f], w1r[f], wx);
                    wxv = wx;
                }
            }
        } else if (wid < 8) {
            // ---- L2: update(i-1) + gather ----
            if (i >= 1 && i <= TT) {
                int j = tid - HH;
                int idx = (j & 3) * DSTR + (j >> 2);
                long long* sA = DSL(1, rp);
                long long* sB = DSL(2, rp);
                TW2 += sA[idx]; sA[idx] = 0;
                TV2 += sB[idx]; sB[idx] = 0;
                float gA = (float)((double)TW2 * INV30);
                float gB = (float)((double)TV2 * INV30);
                syn2 = fmaf(0.95f, syn2, b2r + gA + gB);
                mem2 = fmaf(beta2r, mem2, syn2) - (spk2 ? 1.f : 0.f);
                spk2 = mem2 > 1.0f;
                ull bal = __ballot(spk2 ? 1 : 0);
                ull tog = cur2 ^ bal;
                cur2 = bal;
                if (tog) gatherPair(WTq, V2q, mku(tog), mku(cur2), (wid - 4) << 6, lane,
                                    DSL(3, wp), DSL(2, wp));
            }
        } else {
            // ---- wave 8: x prefetch (issue early, commit late) + F(i-2) ----
            float xpf = 0.f;
            const bool pf = (lane < FF) && ((i + 2) < TT);
            if (pf) xpf = xg[(size_t)(i + 2) * FF + lane];
            if (i >= 2) {
                int tF = i - 2;
                long long* sO = DSL(3, rp);
                float mmax = -3.402823466e38f;
#pragma unroll
                for (int r = 0; r < 4; ++r) {
                    int o = lane + (r << 6);
                    if (o < OO) {
                        int idx = (o & 3) * DSTR + (o >> 2);
                        TOq[r] += sO[idx]; sO[idx] = 0;
                        float ot = (float)((double)TOq[r] * INV30);
                        synO[r] = fmaf(aOr[r], synO[r], ot);
                        memO[r] = fmaf(bOr[r], memO[r], synO[r]) - (spkO[r] ? 1.f : 0.f);
                        spkO[r] = memO[r] > 1.0f;
                        mmax = fmaxf(mmax, memO[r]);
                    } else {
                        int idx = (o & 3) * DSTR + (o >> 2);
                        if (o < HH) sO[idx] = 0;
                    }
                }
#pragma unroll
                for (int off = 32; off; off >>= 1) mmax = fmaxf(mmax, __shfl_xor(mmax, off, 64));
                float ex[4]; float se = 0.f;
#pragma unroll
                for (int r = 0; r < 4; ++r) {
                    int o = lane + (r << 6);
                    ex[r] = (o < OO) ? expf(memO[r] - mmax) : 0.f;
                    se += ex[r];
                }
#pragma unroll
                for (int off = 32; off; off >>= 1) se += __shfl_xor(se, off, 64);
                if (tF > 10) {
#pragma unroll
                    for (int r = 0; r < 4; ++r) accO[r] += ex[r] / se;
                }
            }
            if (pf) xts[i & 1][lane] = xpf;
        }
        __syncthreads();
    }

    if (wid == 8) {
#pragma unroll
        for (int r = 0; r < 4; ++r) {
            int o = lane + (r << 6);
            if (o < OO) out[(size_t)b * OO + o] = accO[r];
        }
    }
}

// one-shot prep: padded 257x256 BIASED-uint fixed-point (2^30) tables
// (value stored = q ^ 0x80000000 = q + 2^31), zero diagonal (V1q/V2q),
// zero row 256, WTq cols >= 200 zero.
__global__ void prep_kernel(const float* __restrict__ Vrec1, const float* __restrict__ Vrec2,
                            const float* __restrict__ W2, const float* __restrict__ Wout,
                            uint* __restrict__ V1q, uint* __restrict__ V2q,
                            uint* __restrict__ W2Tq, uint* __restrict__ WTq) {
    int idx = blockIdx.x * blockDim.x + threadIdx.x;   // 257*256 entries
    if (idx >= 257 * 256) return;
    int r = idx >> 8, c = idx & 255;
    float v1 = 0.f, v2 = 0.f, w2 = 0.f, wo = 0.f;
    if (r < 256) {
        if (r != c) { v1 = Vrec1[r * HH + c]; v2 = Vrec2[r * HH + c]; }
        w2 = W2[c * HH + r];
        if (c < OO) wo = Wout[c * HH + r];
    }
    const float S = 1073741824.0f;   // 2^30
    V1q[idx]  = (uint)__float2int_rn(v1 * S) ^ 0x80000000u;
    V2q[idx]  = (uint)__float2int_rn(v2 * S) ^ 0x80000000u;
    W2Tq[idx] = (uint)__float2int_rn(w2 * S) ^ 0x80000000u;
    WTq[idx]  = (uint)__float2int_rn(wo * S) ^ 0x80000000u;
}

extern "C" void kernel_launch(void* const* d_in, const int* in_sizes, int n_in,
                              void* d_out, int out_size, void* d_ws, size_t ws_size,
                              hipStream_t stream) {
    const float* x       = (const float*)d_in[0];
    const float* W1      = (const float*)d_in[1];
    const float* b1      = (const float*)d_in[2];
    const float* Vrec1   = (const float*)d_in[3];
    const float* beta1   = (const float*)d_in[4];
    const float* W2      = (const float*)d_in[5];
    const float* b2      = (const float*)d_in[6];
    const float* Vrec2   = (const float*)d_in[7];
    const float* beta2   = (const float*)d_in[8];
    const float* Wout    = (const float*)d_in[9];
    const float* alpha_o = (const float*)d_in[10];
    const float* beta_o  = (const float*)d_in[11];

    const int TBL = 257 * 256;       // uint per padded table
    uint* V1q  = (uint*)d_ws;
    uint* V2q  = V1q + TBL;
    uint* W2Tq = V2q + TBL;
    uint* WTq  = W2Tq + TBL;         // total ~1.05 MB of ws

    prep_kernel<<<(TBL + 255) / 256, 256, 0, stream>>>(Vrec1, Vrec2, W2, Wout,
                                                       V1q, V2q, W2Tq, WTq);
    snn_main<<<128, 576, 0, stream>>>(x, W1, b1, beta1, b2, beta2,
                                      V1q, V2q, W2Tq, WTq,
                                      alpha_o, beta_o, (float*)d_out);
}

// Round 6
// 2780.183 us; speedup vs baseline: 1.9929x; 1.9929x over previous
//
#include <hip/hip_runtime.h>

#define TT 1000
#define FF 20
#define HH 256
#define OO 200
#define ZR 256           // zero-row index in padded tables (257 rows x 256 cols)
#define DSTR 68          // padded lane-stride (int64) for delta buffers: bank-conflict-free

typedef unsigned int uint;
typedef unsigned long long ull;

__device__ __forceinline__ int rfl(int v) { return __builtin_amdgcn_readfirstlane(v); }
__device__ __forceinline__ ull mku(ull v) {
    uint lo = (uint)rfl((int)(uint)v), hi = (uint)rfl((int)(uint)(v >> 32));
    return ((ull)hi << 32) | lo;
}

// Self-contained dual-table batch over a 64-bit row mask (wave-uniform): extract
// K rows, issue 2K 16B loads, accumulate. Arrays are local to ONE scope with
// fully unrolled loops -> register-resident (round-5 lesson: pointer-passed
// staging arrays spill to scratch). Tables are BIASED uint (stored = q + 2^31):
// accumulate is plain u64 +=/-= u32 (2 VALU/elem). NEG selects subtract.
template<int K, bool NEG>
__device__ __forceinline__ void gstepU(const uint* __restrict__ tabA, const uint* __restrict__ tabB,
                                       ull& m, int rowbase, int cx, ull* aA, ull* aB) {
    const uint* pA[K];
    const uint* pB[K];
#pragma unroll
    for (int u = 0; u < K; ++u) {
        int k = __ffsll((long long)m) - 1;
        int row = rfl(m ? (rowbase + k) : ZR);
        size_t off = ((size_t)row << 8) + (size_t)cx;
        pA[u] = tabA + off;
        pB[u] = tabB + off;
        m &= (m - 1);
    }
    uint4 va[K], vb[K];
#pragma unroll
    for (int u = 0; u < K; ++u) { va[u] = *(const uint4*)pA[u]; vb[u] = *(const uint4*)pB[u]; }
#pragma unroll
    for (int u = 0; u < K; ++u) {
        if (NEG) {
            aA[0] -= va[u].x; aA[1] -= va[u].y; aA[2] -= va[u].z; aA[3] -= va[u].w;
            aB[0] -= vb[u].x; aB[1] -= vb[u].y; aB[2] -= vb[u].z; aB[3] -= vb[u].w;
        } else {
            aA[0] += va[u].x; aA[1] += va[u].y; aA[2] += va[u].z; aA[3] += va[u].w;
            aB[0] += vb[u].x; aB[1] += vb[u].y; aB[2] += vb[u].z; aB[3] += vb[u].w;
        }
    }
}

// Dual-table gather over 64-bit toggle mask, pos/neg split at mask level:
// pm = toggled-on rows (add), nm = toggled-off rows (subtract). One accumulator
// set; de-bias once via the signed processed-row count (zero-row padding counts
// bias only). Commit via LDS u64 atomics (mod-2^64 exact).
__device__ __forceinline__ void gatherPair(const uint* __restrict__ tabA, const uint* __restrict__ tabB,
                                           ull tog, ull cur, int rowbase, int lane,
                                           long long* dstA, long long* dstB) {
    ull pm = tog & cur;
    ull nm = tog & ~cur;
    ull aA[4] = {0, 0, 0, 0}, aB[4] = {0, 0, 0, 0};
    long long cnt = 0;   // cntP - cntN (incl. ZR padding)
    const int cx = lane << 2;
    while (pm) {
        int pc = rfl(__popcll(pm));
        if (pc > 4)      { gstepU<8, false>(tabA, tabB, pm, rowbase, cx, aA, aB); cnt += 8; }
        else if (pc > 2) { gstepU<4, false>(tabA, tabB, pm, rowbase, cx, aA, aB); cnt += 4; }
        else             { gstepU<2, false>(tabA, tabB, pm, rowbase, cx, aA, aB); cnt += 2; }
    }
    while (nm) {
        int pc = rfl(__popcll(nm));
        if (pc > 4)      { gstepU<8, true>(tabA, tabB, nm, rowbase, cx, aA, aB); cnt -= 8; }
        else if (pc > 2) { gstepU<4, true>(tabA, tabB, nm, rowbase, cx, aA, aB); cnt -= 4; }
        else             { gstepU<2, true>(tabA, tabB, nm, rowbase, cx, aA, aB); cnt -= 2; }
    }
    ull bias = (ull)(cnt << 31);
#pragma unroll
    for (int c = 0; c < 4; ++c) {
        atomicAdd((ull*)&dstA[c * DSTR + lane], aA[c] - bias);
        atomicAdd((ull*)&dstB[c * DSTR + lane], aB[c] - bias);
    }
}

#define INV30 9.31322574615478515625e-10   // 2^-30, exact

// 9-wave (576-thread) SINGLE-barrier pipeline (structure as round 4).
// Rotating zeroed delta buffers (2 slots): gather(i) atomic-adds into slot i&1;
// consumers fold slot (i-1)&1 into REGISTER totals and zero it.
// Waves 0-3: L1 update(i) + ballot (regs) + dual gather (W2Tq,V1q) + wx(i+1).
// Waves 4-7: L2 update(i-1) + ballot + dual gather (WTq,V2q).
// Wave 8: x(i+2) prefetch + output layer F(i-2).
__global__ __launch_bounds__(576, 1) void snn_main(
    const float* __restrict__ x,
    const float* __restrict__ W1, const float* __restrict__ b1,
    const float* __restrict__ beta1,
    const float* __restrict__ b2, const float* __restrict__ beta2,
    const uint* __restrict__ V1q, const uint* __restrict__ V2q,
    const uint* __restrict__ W2Tq, const uint* __restrict__ WTq,
    const float* __restrict__ alpha_out, const float* __restrict__ beta_out,
    float* __restrict__ out)
{
    __shared__ float xts[2][FF];                       // x[t] double buffer
    // delta buffers: drive d (0=V1 1=W2 2=V2 3=O) x slot p x [c][lane] (stride DSTR)
    __shared__ __align__(16) long long dAll[4 * 2 * 4 * DSTR];   // ~17 KB

#define DSL(d, p) (dAll + (((d) * 2 + (p)) * 4) * DSTR)

    const int tid  = threadIdx.x;
    const int wid  = tid >> 6;
    const int lane = tid & 63;
    const int b    = blockIdx.x;
    const float* xg = x + (size_t)b * TT * FF;

    // ---- init ----
    for (int idx = tid; idx < 4 * 2 * 4 * DSTR; idx += 576) dAll[idx] = 0;
    if (tid < FF) { xts[0][tid] = xg[tid]; xts[1][tid] = xg[FF + tid]; }

    // L1 state (tid 0..255): W1 row in registers, drive total in register
    float syn1 = 0.f, mem1 = 0.f, beta1r = 0.f, b1r = 0.f, wxv = 0.f;
    float w1r[FF];
    long long TV1 = 0;
    bool spk1 = false;
    ull cur1 = 0ull;
    if (tid < HH) {
        beta1r = beta1[tid]; b1r = b1[tid];
#pragma unroll
        for (int f = 0; f < FF; ++f) w1r[f] = W1[tid * FF + f];
    }

    // L2 state (tid 256..511)
    float syn2 = 0.f, mem2 = 0.f, beta2r = 0.f, b2r = 0.f;
    long long TW2 = 0, TV2 = 0;
    bool spk2 = false;
    ull cur2 = 0ull;
    if (wid >= 4 && wid < 8) { beta2r = beta2[tid - HH]; b2r = b2[tid - HH]; }

    // output state (wave 8)
    float synO[4] = {0,0,0,0}, memO[4] = {0,0,0,0}, accO[4] = {0,0,0,0};
    float aOr[4] = {0,0,0,0}, bOr[4] = {0,0,0,0};
    long long TOq[4] = {0, 0, 0, 0};
    bool  spkO[4] = {false,false,false,false};
    if (wid == 8) {
#pragma unroll
        for (int r = 0; r < 4; ++r) {
            int o = lane + (r << 6);
            if (o < OO) { aOr[r] = alpha_out[o]; bOr[r] = beta_out[o]; }
        }
    }
    __syncthreads();
    if (tid < HH) {   // wx for t=0
        float wx = b1r;
#pragma unroll
        for (int f = 0; f < FF; ++f) wx = fmaf(xts[0][f], w1r[f], wx);
        wxv = wx;
    }
    __syncthreads();  // protect xts[0] before wave-8's interval-0 rewrite

    for (int i = 0; i < TT + 2; ++i) {
        const int rp = (i - 1) & 1;   // fold slot (written last interval)
        const int wp = i & 1;         // gather-commit slot
        if (wid < 4) {
            // ---- L1: update(i) + gather + wx(i+1) ----
            if (i < TT) {
                long long* slot = DSL(0, rp);
                int idx = (tid & 3) * DSTR + (tid >> 2);
                TV1 += slot[idx]; slot[idx] = 0;
                float g1 = (float)((double)TV1 * INV30);
                syn1 = fmaf(0.95f, syn1, wxv + g1);
                mem1 = fmaf(beta1r, mem1, syn1) - (spk1 ? 1.f : 0.f);
                spk1 = mem1 > 1.0f;
                ull bal = __ballot(spk1 ? 1 : 0);
                ull tog = cur1 ^ bal;
                cur1 = bal;
                if (tog) gatherPair(W2Tq, V1q, mku(tog), mku(cur1), wid << 6, lane,
                                    DSL(1, wp), DSL(0, wp));
                if ((i + 1) < TT) {
                    const float* xx = xts[(i + 1) & 1];
                    float wx = b1r;
#pragma unroll
                    for (int f = 0; f < FF; ++f) wx = fmaf(xx[f], w1r[f], wx);
                    wxv = wx;
                }
            }
        } else if (wid < 8) {
            // ---- L2: update(i-1) + gather ----
            if (i >= 1 && i <= TT) {
                int j = tid - HH;
                int idx = (j & 3) * DSTR + (j >> 2);
                long long* sA = DSL(1, rp);
                long long* sB = DSL(2, rp);
                TW2 += sA[idx]; sA[idx] = 0;
                TV2 += sB[idx]; sB[idx] = 0;
                float gA = (float)((double)TW2 * INV30);
                float gB = (float)((double)TV2 * INV30);
                syn2 = fmaf(0.95f, syn2, b2r + gA + gB);
                mem2 = fmaf(beta2r, mem2, syn2) - (spk2 ? 1.f : 0.f);
                spk2 = mem2 > 1.0f;
                ull bal = __ballot(spk2 ? 1 : 0);
                ull tog = cur2 ^ bal;
                cur2 = bal;
                if (tog) gatherPair(WTq, V2q, mku(tog), mku(cur2), (wid - 4) << 6, lane,
                                    DSL(3, wp), DSL(2, wp));
            }
        } else {
            // ---- wave 8: x prefetch (issue early, commit late) + F(i-2) ----
            float xpf = 0.f;
            const bool pf = (lane < FF) && ((i + 2) < TT);
            if (pf) xpf = xg[(size_t)(i + 2) * FF + lane];
            if (i >= 2) {
                int tF = i - 2;
                long long* sO = DSL(3, rp);
                float mmax = -3.402823466e38f;
#pragma unroll
                for (int r = 0; r < 4; ++r) {
                    int o = lane + (r << 6);
                    if (o < OO) {
                        int idx = (o & 3) * DSTR + (o >> 2);
                        TOq[r] += sO[idx]; sO[idx] = 0;
                        float ot = (float)((double)TOq[r] * INV30);
                        synO[r] = fmaf(aOr[r], synO[r], ot);
                        memO[r] = fmaf(bOr[r], memO[r], synO[r]) - (spkO[r] ? 1.f : 0.f);
                        spkO[r] = memO[r] > 1.0f;
                        mmax = fmaxf(mmax, memO[r]);
                    } else {
                        int idx = (o & 3) * DSTR + (o >> 2);
                        if (o < HH) sO[idx] = 0;
                    }
                }
#pragma unroll
                for (int off = 32; off; off >>= 1) mmax = fmaxf(mmax, __shfl_xor(mmax, off, 64));
                float ex[4]; float se = 0.f;
#pragma unroll
                for (int r = 0; r < 4; ++r) {
                    int o = lane + (r << 6);
                    ex[r] = (o < OO) ? expf(memO[r] - mmax) : 0.f;
                    se += ex[r];
                }
#pragma unroll
                for (int off = 32; off; off >>= 1) se += __shfl_xor(se, off, 64);
                if (tF > 10) {
#pragma unroll
                    for (int r = 0; r < 4; ++r) accO[r] += ex[r] / se;
                }
            }
            if (pf) xts[i & 1][lane] = xpf;
        }
        __syncthreads();
    }

    if (wid == 8) {
#pragma unroll
        for (int r = 0; r < 4; ++r) {
            int o = lane + (r << 6);
            if (o < OO) out[(size_t)b * OO + o] = accO[r];
        }
    }
}

// one-shot prep: padded 257x256 BIASED-uint fixed-point (2^30) tables
// (value stored = q ^ 0x80000000 = q + 2^31), zero diagonal (V1q/V2q),
// zero row 256, WTq cols >= 200 zero.
__global__ void prep_kernel(const float* __restrict__ Vrec1, const float* __restrict__ Vrec2,
                            const float* __restrict__ W2, const float* __restrict__ Wout,
                            uint* __restrict__ V1q, uint* __restrict__ V2q,
                            uint* __restrict__ W2Tq, uint* __restrict__ WTq) {
    int idx = blockIdx.x * blockDim.x + threadIdx.x;   // 257*256 entries
    if (idx >= 257 * 256) return;
    int r = idx >> 8, c = idx & 255;
    float v1 = 0.f, v2 = 0.f, w2 = 0.f, wo = 0.f;
    if (r < 256) {
        if (r != c) { v1 = Vrec1[r * HH + c]; v2 = Vrec2[r * HH + c]; }
        w2 = W2[c * HH + r];
        if (c < OO) wo = Wout[c * HH + r];
    }
    const float S = 1073741824.0f;   // 2^30
    V1q[idx]  = (uint)__float2int_rn(v1 * S) ^ 0x80000000u;
    V2q[idx]  = (uint)__float2int_rn(v2 * S) ^ 0x80000000u;
    W2Tq[idx] = (uint)__float2int_rn(w2 * S) ^ 0x80000000u;
    WTq[idx]  = (uint)__float2int_rn(wo * S) ^ 0x80000000u;
}

extern "C" void kernel_launch(void* const* d_in, const int* in_sizes, int n_in,
                              void* d_out, int out_size, void* d_ws, size_t ws_size,
                              hipStream_t stream) {
    const float* x       = (const float*)d_in[0];
    const float* W1      = (const float*)d_in[1];
    const float* b1      = (const float*)d_in[2];
    const float* Vrec1   = (const float*)d_in[3];
    const float* beta1   = (const float*)d_in[4];
    const float* W2      = (const float*)d_in[5];
    const float* b2      = (const float*)d_in[6];
    const float* Vrec2   = (const float*)d_in[7];
    const float* beta2   = (const float*)d_in[8];
    const float* Wout    = (const float*)d_in[9];
    const float* alpha_o = (const float*)d_in[10];
    const float* beta_o  = (const float*)d_in[11];

    const int TBL = 257 * 256;       // uint per padded table
    uint* V1q  = (uint*)d_ws;
    uint* V2q  = V1q + TBL;
    uint* W2Tq = V2q + TBL;
    uint* WTq  = W2Tq + TBL;         // total ~1.05 MB of ws

    prep_kernel<<<(TBL + 255) / 256, 256, 0, stream>>>(Vrec1, Vrec2, W2, Wout,
                                                       V1q, V2q, W2Tq, WTq);
    snn_main<<<128, 576, 0, stream>>>(x, W1, b1, beta1, b2, beta2,
                                      V1q, V2q, W2Tq, WTq,
                                      alpha_o, beta_o, (float*)d_out);
}

// Round 8
// 1346.950 us; speedup vs baseline: 4.1134x; 2.0641x over previous
//
#include <hip/hip_runtime.h>

#define TT 1000
#define FF 20
#define HH 256
#define OO 200
#define ZR 256           // zero-row index in padded int32 tables (257 rows x 256 cols)
#define DSTR 68          // padded lane-stride (int64) for delta buffers: bank-conflict-free

typedef unsigned int uint;
typedef unsigned long long ull;

__device__ __forceinline__ int rfl(int v) { return __builtin_amdgcn_readfirstlane(v); }
__device__ __forceinline__ ull mku(ull v) {
    uint lo = (uint)rfl((int)(uint)v), hi = (uint)rfl((int)(uint)(v >> 32));
    return ((ull)hi << 32) | lo;
}

// Dual-table signed toggle-gather batch over a 64-BIT mask (single serial chain
// per word instead of lo/hi split -> one load-latency exposure in the sparse-
// toggle common case). Round-4 proven array shapes (N<=8). Sign from cur bit.
// Exact int64 accumulation: (v ^ sm) - sm negates when sm = -1.
template<int N>
__device__ __forceinline__ void gstep2(const int* __restrict__ tabA, const int* __restrict__ tabB,
                                       ull& m, ull cur, int rowbase, int cx,
                                       long long* accA, long long* accB) {
    const int* pA[N];
    const int* pB[N];
    int sm[N];
#pragma unroll
    for (int u = 0; u < N; ++u) {
        int bb = __ffsll((long long)m);
        int k  = (bb ? bb : 1) - 1;
        int row = rfl(bb ? (rowbase + k) : ZR);
        int pos = rfl(bb ? (int)((cur >> k) & 1ull) : 1);
        sm[u] = pos ? 0 : -1;
        size_t off = ((size_t)row << 8) + (size_t)cx;
        pA[u] = tabA + off;
        pB[u] = tabB + off;
        m &= (m - 1);
    }
    int4 va[N], vb[N];
#pragma unroll
    for (int u = 0; u < N; ++u) { va[u] = *(const int4*)pA[u]; vb[u] = *(const int4*)pB[u]; }
#pragma unroll
    for (int u = 0; u < N; ++u) {
        accA[0] += (long long)((va[u].x ^ sm[u]) - sm[u]);
        accA[1] += (long long)((va[u].y ^ sm[u]) - sm[u]);
        accA[2] += (long long)((va[u].z ^ sm[u]) - sm[u]);
        accA[3] += (long long)((va[u].w ^ sm[u]) - sm[u]);
        accB[0] += (long long)((vb[u].x ^ sm[u]) - sm[u]);
        accB[1] += (long long)((vb[u].y ^ sm[u]) - sm[u]);
        accB[2] += (long long)((vb[u].z ^ sm[u]) - sm[u]);
        accB[3] += (long long)((vb[u].w ^ sm[u]) - sm[u]);
    }
}

// Dual-table gather over the full 64-bit toggle mask: single adaptive chain
// (K = 8/4/2 as in round 4). Commit via LDS int64 atomics into the [c][lane]
// padded delta layout (2-way bank aliasing = free).
__device__ __forceinline__ void gatherPair(const int* __restrict__ tabA, const int* __restrict__ tabB,
                                           ull tog, ull cur, int rowbase, int lane,
                                           long long* dstA, long long* dstB) {
    long long accA[4] = {0, 0, 0, 0}, accB[4] = {0, 0, 0, 0};
    const int cx = lane << 2;
    ull m = tog;
    while (m) {
        int pc = rfl(__popcll(m));
        if (pc > 4)      gstep2<8>(tabA, tabB, m, cur, rowbase, cx, accA, accB);
        else if (pc > 2) gstep2<4>(tabA, tabB, m, cur, rowbase, cx, accA, accB);
        else             gstep2<2>(tabA, tabB, m, cur, rowbase, cx, accA, accB);
    }
#pragma unroll
    for (int c = 0; c < 4; ++c) {
        atomicAdd((ull*)&dstA[c * DSTR + lane], (ull)accA[c]);
        atomicAdd((ull*)&dstB[c * DSTR + lane], (ull)accB[c]);
    }
}

#define INV30 9.31322574615478515625e-10   // 2^-30, exact

// 9-wave (576-thread) SINGLE-barrier pipeline (structure identical to round 4).
// Rotating zeroed delta buffers (2 slots): gather(i) atomic-adds into slot i&1;
// consumers fold slot (i-1)&1 into REGISTER totals and zero it.
// Waves 0-3: L1 update(i) + ballot (regs) + dual gather (W2Tq,V1q) + wx(i+1).
// Waves 4-7: L2 update(i-1) + ballot + dual gather (WTq,V2q).
// Wave 8: x(i+2) prefetch + output layer F(i-2).
__global__ __launch_bounds__(576, 1) void snn_main(
    const float* __restrict__ x,
    const float* __restrict__ W1, const float* __restrict__ b1,
    const float* __restrict__ beta1,
    const float* __restrict__ b2, const float* __restrict__ beta2,
    const int* __restrict__ V1q, const int* __restrict__ V2q,
    const int* __restrict__ W2Tq, const int* __restrict__ WTq,
    const float* __restrict__ alpha_out, const float* __restrict__ beta_out,
    float* __restrict__ out)
{
    __shared__ float xts[2][FF];                       // x[t] double buffer
    // delta buffers: drive d (0=V1 1=W2 2=V2 3=O) x slot p x [c][lane] (stride DSTR)
    __shared__ __align__(16) long long dAll[4 * 2 * 4 * DSTR];   // ~17 KB

#define DSL(d, p) (dAll + (((d) * 2 + (p)) * 4) * DSTR)

    const int tid  = threadIdx.x;
    const int wid  = tid >> 6;
    const int lane = tid & 63;
    const int b    = blockIdx.x;
    const float* xg = x + (size_t)b * TT * FF;

    // ---- init ----
    for (int idx = tid; idx < 4 * 2 * 4 * DSTR; idx += 576) dAll[idx] = 0;
    if (tid < FF) { xts[0][tid] = xg[tid]; xts[1][tid] = xg[FF + tid]; }

    // L1 state (tid 0..255): W1 row in registers, drive total in register
    float syn1 = 0.f, mem1 = 0.f, beta1r = 0.f, b1r = 0.f, wxv = 0.f;
    float w1r[FF];
    long long TV1 = 0;
    bool spk1 = false;
    ull cur1 = 0ull;
    if (tid < HH) {
        beta1r = beta1[tid]; b1r = b1[tid];
#pragma unroll
        for (int f = 0; f < FF; ++f) w1r[f] = W1[tid * FF + f];
    }

    // L2 state (tid 256..511)
    float syn2 = 0.f, mem2 = 0.f, beta2r = 0.f, b2r = 0.f;
    long long TW2 = 0, TV2 = 0;
    bool spk2 = false;
    ull cur2 = 0ull;
    if (wid >= 4 && wid < 8) { beta2r = beta2[tid - HH]; b2r = b2[tid - HH]; }

    // output state (wave 8)
    float synO[4] = {0,0,0,0}, memO[4] = {0,0,0,0}, accO[4] = {0,0,0,0};
    float aOr[4] = {0,0,0,0}, bOr[4] = {0,0,0,0};
    long long TOq[4] = {0, 0, 0, 0};
    bool  spkO[4] = {false,false,false,false};
    if (wid == 8) {
#pragma unroll
        for (int r = 0; r < 4; ++r) {
            int o = lane + (r << 6);
            if (o < OO) { aOr[r] = alpha_out[o]; bOr[r] = beta_out[o]; }
        }
    }
    __syncthreads();
    if (tid < HH) {   // wx for t=0
        float wx = b1r;
#pragma unroll
        for (int f = 0; f < FF; ++f) wx = fmaf(xts[0][f], w1r[f], wx);
        wxv = wx;
    }
    __syncthreads();  // protect xts[0] before wave-8's interval-0 rewrite

    for (int i = 0; i < TT + 2; ++i) {
        const int rp = (i - 1) & 1;   // fold slot (written last interval)
        const int wp = i & 1;         // gather-commit slot
        if (wid < 4) {
            // ---- L1: update(i) + gather + wx(i+1) ----
            if (i < TT) {
                long long* slot = DSL(0, rp);
                int idx = (tid & 3) * DSTR + (tid >> 2);
                TV1 += slot[idx]; slot[idx] = 0;
                float g1 = (float)((double)TV1 * INV30);
                syn1 = fmaf(0.95f, syn1, wxv + g1);
                mem1 = fmaf(beta1r, mem1, syn1) - (spk1 ? 1.f : 0.f);
                spk1 = mem1 > 1.0f;
                ull bal = __ballot(spk1 ? 1 : 0);
                ull tog = cur1 ^ bal;
                cur1 = bal;
                if (tog) gatherPair(W2Tq, V1q, mku(tog), mku(cur1), wid << 6, lane,
                                    DSL(1, wp), DSL(0, wp));
                if ((i + 1) < TT) {
                    const float* xx = xts[(i + 1) & 1];
                    float wx = b1r;
#pragma unroll
                    for (int f = 0; f < FF; ++f) wx = fmaf(xx[f], w1r[f], wx);
                    wxv = wx;
                }
            }
        } else if (wid < 8) {
            // ---- L2: update(i-1) + gather ----
            if (i >= 1 && i <= TT) {
                int j = tid - HH;
                int idx = (j & 3) * DSTR + (j >> 2);
                long long* sA = DSL(1, rp);
                long long* sB = DSL(2, rp);
                TW2 += sA[idx]; sA[idx] = 0;
                TV2 += sB[idx]; sB[idx] = 0;
                float gA = (float)((double)TW2 * INV30);
                float gB = (float)((double)TV2 * INV30);
                syn2 = fmaf(0.95f, syn2, b2r + gA + gB);
                mem2 = fmaf(beta2r, mem2, syn2) - (spk2 ? 1.f : 0.f);
                spk2 = mem2 > 1.0f;
                ull bal = __ballot(spk2 ? 1 : 0);
                ull tog = cur2 ^ bal;
                cur2 = bal;
                if (tog) gatherPair(WTq, V2q, mku(tog), mku(cur2), (wid - 4) << 6, lane,
                                    DSL(3, wp), DSL(2, wp));
            }
        } else {
            // ---- wave 8: x prefetch (issue early, commit late) + F(i-2) ----
            float xpf = 0.f;
            const bool pf = (lane < FF) && ((i + 2) < TT);
            if (pf) xpf = xg[(size_t)(i + 2) * FF + lane];
            if (i >= 2) {
                int tF = i - 2;
                long long* sO = DSL(3, rp);
                float mmax = -3.402823466e38f;
#pragma unroll
                for (int r = 0; r < 4; ++r) {
                    int o = lane + (r << 6);
                    if (o < OO) {
                        int idx = (o & 3) * DSTR + (o >> 2);
                        TOq[r] += sO[idx]; sO[idx] = 0;
                        float ot = (float)((double)TOq[r] * INV30);
                        synO[r] = fmaf(aOr[r], synO[r], ot);
                        memO[r] = fmaf(bOr[r], memO[r], synO[r]) - (spkO[r] ? 1.f : 0.f);
                        spkO[r] = memO[r] > 1.0f;
                        mmax = fmaxf(mmax, memO[r]);
                    } else {
                        int idx = (o & 3) * DSTR + (o >> 2);
                        if (o < HH) sO[idx] = 0;
                    }
                }
#pragma unroll
                for (int off = 32; off; off >>= 1) mmax = fmaxf(mmax, __shfl_xor(mmax, off, 64));
                float ex[4]; float se = 0.f;
#pragma unroll
                for (int r = 0; r < 4; ++r) {
                    int o = lane + (r << 6);
                    ex[r] = (o < OO) ? expf(memO[r] - mmax) : 0.f;
                    se += ex[r];
                }
#pragma unroll
                for (int off = 32; off; off >>= 1) se += __shfl_xor(se, off, 64);
                if (tF > 10) {
#pragma unroll
                    for (int r = 0; r < 4; ++r) accO[r] += ex[r] / se;
                }
            }
            if (pf) xts[i & 1][lane] = xpf;
        }
        __syncthreads();
    }

    if (wid == 8) {
#pragma unroll
        for (int r = 0; r < 4; ++r) {
            int o = lane + (r << 6);
            if (o < OO) out[(size_t)b * OO + o] = accO[r];
        }
    }
}

// one-shot prep: padded 257x256 int32 fixed-point (2^30) tables, zero diagonal
// (V1q/V2q), zero row 256, WTq cols >= 200 zero.
__global__ void prep_kernel(const float* __restrict__ Vrec1, const float* __restrict__ Vrec2,
                            const float* __restrict__ W2, const float* __restrict__ Wout,
                            int* __restrict__ V1q, int* __restrict__ V2q,
                            int* __restrict__ W2Tq, int* __restrict__ WTq) {
    int idx = blockIdx.x * blockDim.x + threadIdx.x;   // 257*256 entries
    if (idx >= 257 * 256) return;
    int r = idx >> 8, c = idx & 255;
    float v1 = 0.f, v2 = 0.f, w2 = 0.f, wo = 0.f;
    if (r < 256) {
        if (r != c) { v1 = Vrec1[r * HH + c]; v2 = Vrec2[r * HH + c]; }
        w2 = W2[c * HH + r];
        if (c < OO) wo = Wout[c * HH + r];
    }
    const float S = 1073741824.0f;   // 2^30
    V1q[idx]  = __float2int_rn(v1 * S);
    V2q[idx]  = __float2int_rn(v2 * S);
    W2Tq[idx] = __float2int_rn(w2 * S);
    WTq[idx]  = __float2int_rn(wo * S);
}

extern "C" void kernel_launch(void* const* d_in, const int* in_sizes, int n_in,
                              void* d_out, int out_size, void* d_ws, size_t ws_size,
                              hipStream_t stream) {
    const float* x       = (const float*)d_in[0];
    const float* W1      = (const float*)d_in[1];
    const float* b1      = (const float*)d_in[2];
    const float* Vrec1   = (const float*)d_in[3];
    const float* beta1   = (const float*)d_in[4];
    const float* W2      = (const float*)d_in[5];
    const float* b2      = (const float*)d_in[6];
    const float* Vrec2   = (const float*)d_in[7];
    const float* beta2   = (const float*)d_in[8];
    const float* Wout    = (const float*)d_in[9];
    const float* alpha_o = (const float*)d_in[10];
    const float* beta_o  = (const float*)d_in[11];

    const int TBL = 257 * 256;       // int32 per padded table
    int* V1q  = (int*)d_ws;
    int* V2q  = V1q + TBL;
    int* W2Tq = V2q + TBL;
    int* WTq  = W2Tq + TBL;          // total ~1.05 MB of ws

    prep_kernel<<<(TBL + 255) / 256, 256, 0, stream>>>(Vrec1, Vrec2, W2, Wout,
                                                       V1q, V2q, W2Tq, WTq);
    snn_main<<<128, 576, 0, stream>>>(x, W1, b1, beta1, b2, beta2,
                                      V1q, V2q, W2Tq, WTq,
                                      alpha_o, beta_o, (float*)d_out);
}